// Round 3
// baseline (2585.891 us; speedup 1.0000x reference)
//
#include <hip/hip_runtime.h>
#include <math.h>

// Problem constants (from reference)
#define VSZ   50000
#define EDIM  256
#define HDIM  256
#define H2D   128
#define NCLS  12
#define NB    64
#define NL    512
#define G4    512      // 4*H2
#define NNC   1024     // gates for both directions
#define MM    32768    // NL*NB rows
#define START_TAG 10
#define STOP_TAG  11
#define IMPOSSIBLE -10000.0f

__device__ __forceinline__ float sigmoidf_(float x) {
    return 1.0f / (1.0f + expf(-x));
}

// ---------------------------------------------------------------------------
// K1/K3: gates_x = A @ [W_ih_f;W_ih_r]^T + (b_ih+b_hh)
// A: [rows][256] f32 (optionally gathered via gidx), out: [MM][1024]
// BM=BN=128, BK=32, 256 threads.
// Wave-level 8x8 lane grid over a 64x64 sub-tile: a-reads are 8-way
// broadcast, b-reads 2-way aliased (both conflict-free per m136).
// ---------------------------------------------------------------------------
template <bool GATHER>
__global__ __launch_bounds__(256)
void gemm_gates(const float* __restrict__ A,
                const int*   __restrict__ gidx,
                const float* __restrict__ wf,   // [512][256]
                const float* __restrict__ wr,   // [512][256]
                const float* __restrict__ bihf, const float* __restrict__ bhhf,
                const float* __restrict__ bihr, const float* __restrict__ bhhr,
                float* __restrict__ out)
{
    __shared__ __align__(16) float As[32][132];   // transposed A tile [k][m]
    __shared__ __align__(16) float Bs[32][132];   // transposed B tile [k][n]

    const int tid = threadIdx.x;
    const int n0  = blockIdx.x * 128;   // 0..896 (8 blocks)
    const int m0  = blockIdx.y * 128;   // 0..32640 (256 blocks)

    // wave-level mapping: wave w covers (wm,wn) 64x64 quadrant;
    // lane = 8x8 grid: am = row-octet, bn = col-octet
    const int w    = tid >> 6;
    const int lane = tid & 63;
    const int wm   = w >> 1;
    const int wn   = w & 1;
    const int am   = lane >> 3;
    const int bn   = lane & 7;
    const int ma   = wm * 64 + am * 8;   // row frag base within tile
    const int nb   = wn * 64 + bn * 8;   // col frag base within tile

    float acc[8][8];
#pragma unroll
    for (int i = 0; i < 8; ++i)
#pragma unroll
        for (int j = 0; j < 8; ++j) acc[i][j] = 0.0f;

    const bool   fwdside = (n0 < 512);
    const float* wsrc    = fwdside ? wf : wr;
    const int    nbase   = fwdside ? n0 : (n0 - 512);

    // Hoist gather indices (row set per thread is kt-invariant)
    int srcA[4];
#pragma unroll
    for (int it = 0; it < 4; ++it) {
        int li  = tid + it * 256;
        int row = m0 + (li >> 3);
        srcA[it] = GATHER ? gidx[row] : row;
    }

    for (int kt = 0; kt < 8; ++kt) {
        // ---- stage A tile (128 rows x 32 k), transposed ----
#pragma unroll
        for (int it = 0; it < 4; ++it) {
            int li = tid + it * 256;
            int r  = li >> 3;
            int c4 = li & 7;
            float4 v = ((const float4*)A)[(size_t)srcA[it] * 64 + kt * 8 + c4];
            As[c4 * 4 + 0][r] = v.x;
            As[c4 * 4 + 1][r] = v.y;
            As[c4 * 4 + 2][r] = v.z;
            As[c4 * 4 + 3][r] = v.w;
        }
        // ---- stage B tile (128 n-rows x 32 k), transposed ----
#pragma unroll
        for (int it = 0; it < 4; ++it) {
            int li = tid + it * 256;
            int r  = li >> 3;
            int c4 = li & 7;
            float4 v = ((const float4*)wsrc)[(size_t)(nbase + r) * 64 + kt * 8 + c4];
            Bs[c4 * 4 + 0][r] = v.x;
            Bs[c4 * 4 + 1][r] = v.y;
            Bs[c4 * 4 + 2][r] = v.z;
            Bs[c4 * 4 + 3][r] = v.w;
        }
        __syncthreads();

#pragma unroll
        for (int k = 0; k < 32; ++k) {
            float a[8], b[8];
            *(float4*)&a[0] = *(const float4*)&As[k][ma];
            *(float4*)&a[4] = *(const float4*)&As[k][ma + 4];
            *(float4*)&b[0] = *(const float4*)&Bs[k][nb];
            *(float4*)&b[4] = *(const float4*)&Bs[k][nb + 4];
#pragma unroll
            for (int i = 0; i < 8; ++i)
#pragma unroll
                for (int j = 0; j < 8; ++j)
                    acc[i][j] = fmaf(a[i], b[j], acc[i][j]);
        }
        __syncthreads();
    }

    // bias per output column (b_ih + b_hh), then store
    float bias[8];
#pragma unroll
    for (int j = 0; j < 8; ++j) {
        int gn = n0 + nb + j;
        bias[j] = fwdside ? (bihf[gn] + bhhf[gn]) : (bihr[gn - 512] + bhhr[gn - 512]);
    }
#pragma unroll
    for (int i = 0; i < 8; ++i) {
        int m = m0 + ma + i;
        float4 s0, s1;
        s0.x = acc[i][0] + bias[0]; s0.y = acc[i][1] + bias[1];
        s0.z = acc[i][2] + bias[2]; s0.w = acc[i][3] + bias[3];
        s1.x = acc[i][4] + bias[4]; s1.y = acc[i][5] + bias[5];
        s1.z = acc[i][6] + bias[6]; s1.w = acc[i][7] + bias[7];
        float4* op = (float4*)(out + (size_t)m * NNC + n0 + nb);
        op[0] = s0;
        op[1] = s1;
    }
}

// ---------------------------------------------------------------------------
// K2/K4: LSTM recurrence, register-reuse version (T=2).
// 128 blocks = 64 batch slots x 2 directions; 256 threads.
// Thread j owns TWO gate rows: j and j+256:
//   j <  128 : i-gate j   and g-gate j       (sigmoid, tanh)
//   j >= 128 : f-gate j-128 and o-gate j-128 (sigmoid, sigmoid)
// One ds_read_b128 of h feeds 8 FMAs (2 gates x 4). 8 accumulators break
// the dependent FMA chain. Weights: 256 VGPRs/thread (1 wave/SIMD).
// ---------------------------------------------------------------------------
__global__ __launch_bounds__(256, 1)
void lstm_rec(const float* __restrict__ gx,    // [MM][1024]
              const float* __restrict__ whf,   // [512][128]
              const float* __restrict__ whr,
              const float* __restrict__ h0,    // [2][64][128]
              const float* __restrict__ c0,
              float* __restrict__ out)         // [MM][256]
{
    __shared__ __align__(16) float h_lds[H2D];
    __shared__ __align__(16) float fo[256];    // [0:128)=f, [128:256)=o

    const int j   = threadIdx.x;               // 0..255
    const int dir = blockIdx.x >> 6;           // 0 fwd, 1 rev
    const int bb  = blockIdx.x & 63;
    const float* W = dir ? whr : whf;

    const int g0 = j;          // row in [0,256)
    const int g1 = j + 256;    // row in [256,512)

    // two W_hh rows -> registers (256 VGPRs)
    float w0[H2D], w1[H2D];
#pragma unroll
    for (int k4 = 0; k4 < 32; ++k4) {
        float4 v0 = ((const float4*)W)[(size_t)g0 * 32 + k4];
        float4 v1 = ((const float4*)W)[(size_t)g1 * 32 + k4];
        w0[4 * k4 + 0] = v0.x; w0[4 * k4 + 1] = v0.y;
        w0[4 * k4 + 2] = v0.z; w0[4 * k4 + 3] = v0.w;
        w1[4 * k4 + 0] = v1.x; w1[4 * k4 + 1] = v1.y;
        w1[4 * k4 + 2] = v1.z; w1[4 * k4 + 3] = v1.w;
    }

    float creg = 0.0f;
    if (j < H2D) {
        h_lds[j] = h0[dir * (NB * H2D) + bb * H2D + j];
        creg     = c0[dir * (NB * H2D) + bb * H2D + j];
    }
    __syncthreads();

    const float4* h4 = (const float4*)h_lds;
    const bool low = (j < H2D);                // wave-uniform (waves 0-1)

    for (int ti = 0; ti < NL; ++ti) {
        const int t = dir ? (NL - 1 - ti) : ti;
        const size_t m = (size_t)t * NB + bb;

        // issue gate-input loads early (independent of the dot)
        const float gx0 = gx[m * NNC + dir * 512 + g0];
        const float gx1 = gx[m * NNC + dir * 512 + g1];

        float d00 = 0.f, d01 = 0.f, d02 = 0.f, d03 = 0.f;
        float d10 = 0.f, d11 = 0.f, d12 = 0.f, d13 = 0.f;
#pragma unroll
        for (int k4 = 0; k4 < 32; ++k4) {
            const float4 hv = h4[k4];          // LDS broadcast (free)
            d00 = fmaf(w0[4 * k4 + 0], hv.x, d00);
            d01 = fmaf(w0[4 * k4 + 1], hv.y, d01);
            d02 = fmaf(w0[4 * k4 + 2], hv.z, d02);
            d03 = fmaf(w0[4 * k4 + 3], hv.w, d03);
            d10 = fmaf(w1[4 * k4 + 0], hv.x, d10);
            d11 = fmaf(w1[4 * k4 + 1], hv.y, d11);
            d12 = fmaf(w1[4 * k4 + 2], hv.z, d12);
            d13 = fmaf(w1[4 * k4 + 3], hv.w, d13);
        }
        const float pre0 = ((d00 + d01) + (d02 + d03)) + gx0;
        const float pre1 = ((d10 + d11) + (d12 + d13)) + gx1;

        const float act0 = sigmoidf_(pre0);                      // i or f
        const float act1 = low ? tanhf(pre1) : sigmoidf_(pre1);  // g or o

        if (!low) {
            fo[j - 128] = act0;   // f
            fo[j]       = act1;   // o   (j in [128,256))
        }
        __syncthreads();

        if (low) {
            const float fg = fo[j];
            const float og = fo[j + 128];
            creg = fg * creg + act0 * act1;            // f*c + i*g
            const float hnew = og * tanhf(creg);
            h_lds[j] = hnew;
            out[m * HDIM + dir * H2D + j] = hnew;
        }
        __syncthreads();
    }
}

// ---------------------------------------------------------------------------
// K5: feats = out2 @ w_out^T + b_out   (M=32768, N=12, K=256)
// ---------------------------------------------------------------------------
__global__ __launch_bounds__(256)
void feats_kernel(const float* __restrict__ out2,
                  const float* __restrict__ w_out,   // [12][256]
                  const float* __restrict__ b_out,
                  float* __restrict__ feats)         // [MM][12]
{
    __shared__ __align__(16) float wl[NCLS * HDIM];
    const int tid = threadIdx.x;
#pragma unroll
    for (int i = 0; i < NCLS; ++i) wl[tid + i * 256] = w_out[tid + i * 256];
    __syncthreads();

    const int m = blockIdx.x * 256 + tid;
    float acc[NCLS];
#pragma unroll
    for (int c = 0; c < NCLS; ++c) acc[c] = 0.0f;

    const float4* x4 = (const float4*)out2 + (size_t)m * 64;
    const float4* w4 = (const float4*)wl;
    for (int k4 = 0; k4 < 64; ++k4) {
        float4 x = x4[k4];
#pragma unroll
        for (int c = 0; c < NCLS; ++c) {
            float4 wv = w4[c * 64 + k4];              // LDS broadcast
            acc[c] = fmaf(x.x, wv.x, acc[c]);
            acc[c] = fmaf(x.y, wv.y, acc[c]);
            acc[c] = fmaf(x.z, wv.z, acc[c]);
            acc[c] = fmaf(x.w, wv.w, acc[c]);
        }
    }
#pragma unroll
    for (int c = 0; c < NCLS; ++c)
        feats[(size_t)m * NCLS + c] = acc[c] + b_out[c];
}

// ---------------------------------------------------------------------------
// K6: Viterbi forward. One block (one wave) per batch slot b.
// ---------------------------------------------------------------------------
__global__ __launch_bounds__(64)
void viterbi_fwd(const float* __restrict__ feats,
                 const float* __restrict__ masks,   // [B][L]
                 const float* __restrict__ trans,   // [12][12]
                 float* __restrict__ best_score,    // d_out[0:64]
                 unsigned char* __restrict__ bps,   // [L][B][12]
                 int* __restrict__ best_tag)        // ws
{
    const int b    = blockIdx.x;
    const int lane = threadIdx.x;

    float tr[NCLS];
#pragma unroll
    for (int jj = 0; jj < NCLS; ++jj)
        tr[jj] = (lane < NCLS) ? trans[lane * NCLS + jj] : 0.0f;

    float msv = (lane == START_TAG) ? 0.0f : IMPOSSIBLE;

    for (int t = 0; t < NL; ++t) {
        const float emit = (lane < NCLS) ? feats[((size_t)b * NL + t) * NCLS + lane] : 0.0f;
        const float mt   = masks[b * NL + t];

        float best = -3.4e38f;
        int   bj   = 0;
#pragma unroll
        for (int jj = 0; jj < NCLS; ++jj) {
            float msj = __shfl(msv, jj);
            float v   = msj + tr[jj];
            if (v > best) { best = v; bj = jj; }   // strict > keeps first max
        }
        const float sc = best + emit;
        msv = mt * sc + (1.0f - mt) * msv;
        if (lane < NCLS)
            bps[((size_t)t * NB + b) * NCLS + lane] = (unsigned char)bj;
    }

    const float fin = (lane < NCLS) ? (msv + trans[STOP_TAG * NCLS + lane]) : -3.4e38f;
    float bv = -3.4e38f;
    int   bt = 0;
#pragma unroll
    for (int jj = 0; jj < NCLS; ++jj) {
        float v = __shfl(fin, jj);
        if (v > bv) { bv = v; bt = jj; }
    }
    if (lane == 0) {
        best_score[b] = bv;
        best_tag[b]   = bt;
    }
}

// ---------------------------------------------------------------------------
// K7: backtrace. Thread b walks its chain. path written as float.
// ---------------------------------------------------------------------------
__global__ __launch_bounds__(64)
void backtrace(const unsigned char* __restrict__ bps,
               const int* __restrict__ best_tag,
               const float* __restrict__ masks,
               float* __restrict__ path_out)        // d_out + 64, [B][L]
{
    const int b = threadIdx.x;
    float s = 0.0f;
    for (int t = 0; t < NL; ++t) s += masks[b * NL + t];
    const int len  = (int)(s + 0.5f);
    const int btag = best_tag[b];

    int cur = btag;
    for (int t = NL - 1; t >= 0; --t) {
        const int tb  = (t == NL - 1) ? (NL - 1) : (t + 1);   // bps_next[t]
        const int nxt = bps[((size_t)tb * NB + b) * NCLS + cur];
        const int val = (t >= len - 1) ? btag : nxt;
        cur = val;
        path_out[(size_t)b * NL + t] = (t < len) ? (float)val : 0.0f;
    }
}

// ---------------------------------------------------------------------------
extern "C" void kernel_launch(void* const* d_in, const int* in_sizes, int n_in,
                              void* d_out, int out_size, void* d_ws, size_t ws_size,
                              hipStream_t stream)
{
    const int*   sentence = (const int*)  d_in[0];
    const float* masks    = (const float*)d_in[1];
    const float* emb      = (const float*)d_in[2];
    const float* w_ih_f1  = (const float*)d_in[3];
    const float* w_hh_f1  = (const float*)d_in[4];
    const float* b_ih_f1  = (const float*)d_in[5];
    const float* b_hh_f1  = (const float*)d_in[6];
    const float* w_ih_r1  = (const float*)d_in[7];
    const float* w_hh_r1  = (const float*)d_in[8];
    const float* b_ih_r1  = (const float*)d_in[9];
    const float* b_hh_r1  = (const float*)d_in[10];
    const float* w_ih_f2  = (const float*)d_in[11];
    const float* w_hh_f2  = (const float*)d_in[12];
    const float* b_ih_f2  = (const float*)d_in[13];
    const float* b_hh_f2  = (const float*)d_in[14];
    const float* w_ih_r2  = (const float*)d_in[15];
    const float* w_hh_r2  = (const float*)d_in[16];
    const float* b_ih_r2  = (const float*)d_in[17];
    const float* b_hh_r2  = (const float*)d_in[18];
    const float* w_out    = (const float*)d_in[19];
    const float* b_out    = (const float*)d_in[20];
    const float* trans    = (const float*)d_in[21];
    const float* h0_1     = (const float*)d_in[22];
    const float* c0_1     = (const float*)d_in[23];
    const float* h0_2     = (const float*)d_in[24];
    const float* c0_2     = (const float*)d_in[25];

    // workspace layout (f32); gx reused between layers
    float* gx    = (float*)d_ws;                       // [32768][1024]  134.2 MB
    float* out1  = gx   + (size_t)MM * NNC;            // [32768][256]    33.6 MB
    float* out2  = out1 + (size_t)MM * HDIM;           // [32768][256]    33.6 MB
    float* feats = out2 + (size_t)MM * HDIM;           // [32768][12]      1.6 MB
    int*   btag  = (int*)(feats + (size_t)MM * NCLS);  // [64]
    unsigned char* bps = (unsigned char*)(btag + 64);  // [512][64][12]  384 KB

    dim3 gemm_grid(NNC / 128, MM / 128);   // (8, 256)

    // Layer 1: input gates (gathered through sentence) -> recurrence
    gemm_gates<true><<<gemm_grid, 256, 0, stream>>>(
        emb, sentence, w_ih_f1, w_ih_r1, b_ih_f1, b_hh_f1, b_ih_r1, b_hh_r1, gx);
    lstm_rec<<<128, 256, 0, stream>>>(gx, w_hh_f1, w_hh_r1, h0_1, c0_1, out1);

    // Layer 2
    gemm_gates<false><<<gemm_grid, 256, 0, stream>>>(
        out1, nullptr, w_ih_f2, w_ih_r2, b_ih_f2, b_hh_f2, b_ih_r2, b_hh_r2, gx);
    lstm_rec<<<128, 256, 0, stream>>>(gx, w_hh_f2, w_hh_r2, h0_2, c0_2, out2);

    // Projection + CRF
    feats_kernel<<<MM / 256, 256, 0, stream>>>(out2, w_out, b_out, feats);
    viterbi_fwd<<<NB, 64, 0, stream>>>(feats, masks, trans, (float*)d_out, bps, btag);
    backtrace<<<1, 64, 0, stream>>>(bps, btag, masks, (float*)d_out + 64);
}

// Round 4
// 1871.518 us; speedup vs baseline: 1.3817x; 1.3817x over previous
//
#include <hip/hip_runtime.h>
#include <math.h>

// Problem constants (from reference)
#define VSZ   50000
#define EDIM  256
#define HDIM  256
#define H2D   128
#define NCLS  12
#define NB    64
#define NL    512
#define G4    512      // 4*H2
#define NNC   1024     // gates for both directions
#define MM    32768    // NL*NB rows
#define START_TAG 10
#define STOP_TAG  11
#define IMPOSSIBLE -10000.0f

__device__ __forceinline__ float sigmoidf_(float x) {
    return 1.0f / (1.0f + expf(-x));
}

// ---------------------------------------------------------------------------
// K1/K3: gates_x = A @ [W_ih_f;W_ih_r]^T + (b_ih+b_hh)
// A: [rows][256] f32 (optionally gathered via gidx), out: [MM][1024]
// BM=BN=128, BK=32, 256 threads. Wave-level 8x8 lane grid over a 64x64
// sub-tile: a-reads 8-way broadcast, b-reads 2-way aliased (free, m136).
// ---------------------------------------------------------------------------
template <bool GATHER>
__global__ __launch_bounds__(256)
void gemm_gates(const float* __restrict__ A,
                const int*   __restrict__ gidx,
                const float* __restrict__ wf,   // [512][256]
                const float* __restrict__ wr,   // [512][256]
                const float* __restrict__ bihf, const float* __restrict__ bhhf,
                const float* __restrict__ bihr, const float* __restrict__ bhhr,
                float* __restrict__ out)
{
    __shared__ __align__(16) float As[32][132];   // transposed A tile [k][m]
    __shared__ __align__(16) float Bs[32][132];   // transposed B tile [k][n]

    const int tid = threadIdx.x;
    const int n0  = blockIdx.x * 128;
    const int m0  = blockIdx.y * 128;

    const int w    = tid >> 6;
    const int lane = tid & 63;
    const int wm   = w >> 1;
    const int wn   = w & 1;
    const int am   = lane >> 3;
    const int bn   = lane & 7;
    const int ma   = wm * 64 + am * 8;
    const int nb   = wn * 64 + bn * 8;

    float acc[8][8];
#pragma unroll
    for (int i = 0; i < 8; ++i)
#pragma unroll
        for (int jj = 0; jj < 8; ++jj) acc[i][jj] = 0.0f;

    const bool   fwdside = (n0 < 512);
    const float* wsrc    = fwdside ? wf : wr;
    const int    nbase   = fwdside ? n0 : (n0 - 512);

    int srcA[4];
#pragma unroll
    for (int it = 0; it < 4; ++it) {
        int li  = tid + it * 256;
        int row = m0 + (li >> 3);
        srcA[it] = GATHER ? gidx[row] : row;
    }

    for (int kt = 0; kt < 8; ++kt) {
#pragma unroll
        for (int it = 0; it < 4; ++it) {
            int li = tid + it * 256;
            int r  = li >> 3;
            int c4 = li & 7;
            float4 v = ((const float4*)A)[(size_t)srcA[it] * 64 + kt * 8 + c4];
            As[c4 * 4 + 0][r] = v.x;
            As[c4 * 4 + 1][r] = v.y;
            As[c4 * 4 + 2][r] = v.z;
            As[c4 * 4 + 3][r] = v.w;
        }
#pragma unroll
        for (int it = 0; it < 4; ++it) {
            int li = tid + it * 256;
            int r  = li >> 3;
            int c4 = li & 7;
            float4 v = ((const float4*)wsrc)[(size_t)(nbase + r) * 64 + kt * 8 + c4];
            Bs[c4 * 4 + 0][r] = v.x;
            Bs[c4 * 4 + 1][r] = v.y;
            Bs[c4 * 4 + 2][r] = v.z;
            Bs[c4 * 4 + 3][r] = v.w;
        }
        __syncthreads();

#pragma unroll
        for (int k = 0; k < 32; ++k) {
            float a[8], b[8];
            *(float4*)&a[0] = *(const float4*)&As[k][ma];
            *(float4*)&a[4] = *(const float4*)&As[k][ma + 4];
            *(float4*)&b[0] = *(const float4*)&Bs[k][nb];
            *(float4*)&b[4] = *(const float4*)&Bs[k][nb + 4];
#pragma unroll
            for (int i = 0; i < 8; ++i)
#pragma unroll
                for (int jj = 0; jj < 8; ++jj)
                    acc[i][jj] = fmaf(a[i], b[jj], acc[i][jj]);
        }
        __syncthreads();
    }

    float bias[8];
#pragma unroll
    for (int jj = 0; jj < 8; ++jj) {
        int gn = n0 + nb + jj;
        bias[jj] = fwdside ? (bihf[gn] + bhhf[gn]) : (bihr[gn - 512] + bhhr[gn - 512]);
    }
#pragma unroll
    for (int i = 0; i < 8; ++i) {
        int m = m0 + ma + i;
        float4 s0, s1;
        s0.x = acc[i][0] + bias[0]; s0.y = acc[i][1] + bias[1];
        s0.z = acc[i][2] + bias[2]; s0.w = acc[i][3] + bias[3];
        s1.x = acc[i][4] + bias[4]; s1.y = acc[i][5] + bias[5];
        s1.z = acc[i][6] + bias[6]; s1.w = acc[i][7] + bias[7];
        float4* op = (float4*)(out + (size_t)m * NNC + n0 + nb);
        op[0] = s0;
        op[1] = s1;
    }
}

// ---------------------------------------------------------------------------
// K2/K4: LSTM recurrence v3. 128 blocks = 64 batch x 2 dir; 512 threads.
// Thread j owns gate row j. Weights live in 128 VGPRs, PINNED via empty
// asm so the compiler cannot rematerialize the global loads per step
// (R1: VGPR=80 -> weights re-streamed from L2 at 34 TB/s = L2-bound).
// launch_bounds(512,2) caps VGPR at 256: ~75 spare regs let the compiler
// keep many h ds_reads in flight, and 8 waves = 2 waves/SIMD restores TLP
// (R2: VGPR=256 cap-hit + 1 wave/SIMD -> serialized LDS reads, 4030 cyc/step).
// ---------------------------------------------------------------------------
__global__ __launch_bounds__(512, 2)
void lstm_rec(const float* __restrict__ gx,    // [MM][1024]
              const float* __restrict__ whf,   // [512][128]
              const float* __restrict__ whr,
              const float* __restrict__ h0,    // [2][64][128]
              const float* __restrict__ c0,
              float* __restrict__ out)         // [MM][256]
{
    __shared__ __align__(16) float h_lds[H2D];
    __shared__ __align__(16) float gates[G4];

    const int j   = threadIdx.x;               // 0..511 gate row
    const int dir = blockIdx.x >> 6;           // 0 fwd, 1 rev
    const int bb  = blockIdx.x & 63;
    const float* W = dir ? whr : whf;

    // W_hh row j -> 128 VGPRs
    float4 w4[32];
#pragma unroll
    for (int k = 0; k < 32; ++k)
        w4[k] = ((const float4*)W)[(size_t)j * 32 + k];
    // Pin: opaque op makes per-step reload-from-global impossible.
#pragma unroll
    for (int k = 0; k < 32; ++k)
        asm volatile("" : "+v"(w4[k].x), "+v"(w4[k].y), "+v"(w4[k].z), "+v"(w4[k].w));

    float creg = 0.0f;
    if (j < H2D) {
        h_lds[j] = h0[dir * (NB * H2D) + bb * H2D + j];
        creg     = c0[dir * (NB * H2D) + bb * H2D + j];
    }
    __syncthreads();

    const float4* h4 = (const float4*)h_lds;
    const int chunk = j >> 7;                  // wave-uniform: 0:i 1:f 2:g 3:o
    const size_t gx_off = (size_t)dir * 512 + j;

    // prologue: prefetch first step's gate input
    const int tfirst = dir ? (NL - 1) : 0;
    float gx_cur = gx[((size_t)tfirst * NB + bb) * NNC + gx_off];

    for (int ti = 0; ti < NL; ++ti) {
        const int t = dir ? (NL - 1 - ti) : ti;
        const size_t m = (size_t)t * NB + bb;

        float d0 = 0.f, d1 = 0.f, d2 = 0.f, d3 = 0.f;
#pragma unroll
        for (int k = 0; k < 32; ++k) {
            const float4 hv = h4[k];           // LDS broadcast
            d0 = fmaf(w4[k].x, hv.x, d0);
            d1 = fmaf(w4[k].y, hv.y, d1);
            d2 = fmaf(w4[k].z, hv.z, d2);
            d3 = fmaf(w4[k].w, hv.w, d3);
        }
        const float pre = ((d0 + d1) + (d2 + d3)) + gx_cur;
        const float act = (chunk == 2) ? tanhf(pre) : sigmoidf_(pre);
        gates[j] = act;
        __syncthreads();

        // prefetch next step's gx: independent of h, hides HBM/L3 latency
        // under the c-update + barrier + next dot
        if (ti + 1 < NL) {
            const int tn = dir ? (NL - 2 - ti) : (ti + 1);
            gx_cur = gx[((size_t)tn * NB + bb) * NNC + gx_off];
        }

        if (j < H2D) {
            const float ig = gates[j];
            const float fg = gates[j + 128];
            const float gg = gates[j + 256];
            const float og = gates[j + 384];
            creg = fg * creg + ig * gg;
            const float hnew = og * tanhf(creg);
            h_lds[j] = hnew;
            out[m * HDIM + dir * H2D + j] = hnew;
        }
        __syncthreads();
    }
}

// ---------------------------------------------------------------------------
// K5: feats = out2 @ w_out^T + b_out   (M=32768, N=12, K=256)
// ---------------------------------------------------------------------------
__global__ __launch_bounds__(256)
void feats_kernel(const float* __restrict__ out2,
                  const float* __restrict__ w_out,   // [12][256]
                  const float* __restrict__ b_out,
                  float* __restrict__ feats)         // [MM][12]
{
    __shared__ __align__(16) float wl[NCLS * HDIM];
    const int tid = threadIdx.x;
#pragma unroll
    for (int i = 0; i < NCLS; ++i) wl[tid + i * 256] = w_out[tid + i * 256];
    __syncthreads();

    const int m = blockIdx.x * 256 + tid;
    float acc[NCLS];
#pragma unroll
    for (int c = 0; c < NCLS; ++c) acc[c] = 0.0f;

    const float4* x4 = (const float4*)out2 + (size_t)m * 64;
    const float4* w4 = (const float4*)wl;
    for (int k4 = 0; k4 < 64; ++k4) {
        float4 x = x4[k4];
#pragma unroll
        for (int c = 0; c < NCLS; ++c) {
            float4 wv = w4[c * 64 + k4];              // LDS broadcast
            acc[c] = fmaf(x.x, wv.x, acc[c]);
            acc[c] = fmaf(x.y, wv.y, acc[c]);
            acc[c] = fmaf(x.z, wv.z, acc[c]);
            acc[c] = fmaf(x.w, wv.w, acc[c]);
        }
    }
#pragma unroll
    for (int c = 0; c < NCLS; ++c)
        feats[(size_t)m * NCLS + c] = acc[c] + b_out[c];
}

// ---------------------------------------------------------------------------
// K6: Viterbi forward + backtrace, fused. One wave per batch slot.
// Backpointers live in LDS (512x12 bytes) -> no global round-trip, and the
// serial backtrace walk reads ~70-cyc LDS instead of ~300-cyc L2.
// Integer logic identical to the split version (numeric-neutral fusion).
// ---------------------------------------------------------------------------
__global__ __launch_bounds__(64)
void viterbi_crf(const float* __restrict__ feats,
                 const float* __restrict__ masks,   // [B][L]
                 const float* __restrict__ trans,   // [12][12]
                 float* __restrict__ out)           // [0:64) score, [64:) path
{
    __shared__ unsigned char bpl[NL][NCLS];
    __shared__ float pathl[NL];

    const int b    = blockIdx.x;
    const int lane = threadIdx.x;

    float tr[NCLS];
#pragma unroll
    for (int jj = 0; jj < NCLS; ++jj)
        tr[jj] = (lane < NCLS) ? trans[lane * NCLS + jj] : 0.0f;

    float msv = (lane == START_TAG) ? 0.0f : IMPOSSIBLE;
    float len = 0.0f;

    // prefetch t=0
    float emit_n = (lane < NCLS) ? feats[((size_t)b * NL) * NCLS + lane] : 0.0f;
    float mt_n   = masks[b * NL];

    for (int t = 0; t < NL; ++t) {
        const float emit = emit_n;
        const float mt   = mt_n;
        if (t + 1 < NL) {
            emit_n = (lane < NCLS) ? feats[((size_t)b * NL + t + 1) * NCLS + lane] : 0.0f;
            mt_n   = masks[b * NL + t + 1];
        }
        len += mt;

        float best = -3.4e38f;
        int   bj   = 0;
#pragma unroll
        for (int jj = 0; jj < NCLS; ++jj) {
            float msj = __shfl(msv, jj);
            float v   = msj + tr[jj];
            if (v > best) { best = v; bj = jj; }   // strict > keeps first max
        }
        const float sc = best + emit;
        msv = mt * sc + (1.0f - mt) * msv;
        if (lane < NCLS)
            bpl[t][lane] = (unsigned char)bj;
    }

    const float fin = (lane < NCLS) ? (msv + trans[STOP_TAG * NCLS + lane]) : -3.4e38f;
    float bv = -3.4e38f;
    int   bt = 0;
#pragma unroll
    for (int jj = 0; jj < NCLS; ++jj) {
        float v = __shfl(fin, jj);
        if (v > bv) { bv = v; bt = jj; }
    }
    if (lane == 0) out[b] = bv;

    const int ilen = (int)(len + 0.5f);        // lane-uniform

    __syncthreads();   // bpl writes -> walk reads

    // backtrace walk (uniform across lanes; lane 0 records)
    int cur = bt;
    for (int t = NL - 1; t >= 0; --t) {
        const int tb  = (t == NL - 1) ? (NL - 1) : (t + 1);
        const int nxt = bpl[tb][cur];
        const int val = (t >= ilen - 1) ? bt : nxt;
        cur = val;
        if (lane == 0) pathl[t] = (t < ilen) ? (float)val : 0.0f;
    }
    __syncthreads();   // pathl writes -> vector copy

    float* po = out + 64 + (size_t)b * NL;
#pragma unroll
    for (int i = 0; i < NL / 64; ++i)
        po[lane + i * 64] = pathl[lane + i * 64];
}

// ---------------------------------------------------------------------------
extern "C" void kernel_launch(void* const* d_in, const int* in_sizes, int n_in,
                              void* d_out, int out_size, void* d_ws, size_t ws_size,
                              hipStream_t stream)
{
    const int*   sentence = (const int*)  d_in[0];
    const float* masks    = (const float*)d_in[1];
    const float* emb      = (const float*)d_in[2];
    const float* w_ih_f1  = (const float*)d_in[3];
    const float* w_hh_f1  = (const float*)d_in[4];
    const float* b_ih_f1  = (const float*)d_in[5];
    const float* b_hh_f1  = (const float*)d_in[6];
    const float* w_ih_r1  = (const float*)d_in[7];
    const float* w_hh_r1  = (const float*)d_in[8];
    const float* b_ih_r1  = (const float*)d_in[9];
    const float* b_hh_r1  = (const float*)d_in[10];
    const float* w_ih_f2  = (const float*)d_in[11];
    const float* w_hh_f2  = (const float*)d_in[12];
    const float* b_ih_f2  = (const float*)d_in[13];
    const float* b_hh_f2  = (const float*)d_in[14];
    const float* w_ih_r2  = (const float*)d_in[15];
    const float* w_hh_r2  = (const float*)d_in[16];
    const float* b_ih_r2  = (const float*)d_in[17];
    const float* b_hh_r2  = (const float*)d_in[18];
    const float* w_out    = (const float*)d_in[19];
    const float* b_out    = (const float*)d_in[20];
    const float* trans    = (const float*)d_in[21];
    const float* h0_1     = (const float*)d_in[22];
    const float* c0_1     = (const float*)d_in[23];
    const float* h0_2     = (const float*)d_in[24];
    const float* c0_2     = (const float*)d_in[25];

    // workspace layout (f32); gx reused between layers
    float* gx    = (float*)d_ws;                       // [32768][1024]  134.2 MB
    float* out1  = gx   + (size_t)MM * NNC;            // [32768][256]    33.6 MB
    float* out2  = out1 + (size_t)MM * HDIM;           // [32768][256]    33.6 MB
    float* feats = out2 + (size_t)MM * HDIM;           // [32768][12]      1.6 MB

    dim3 gemm_grid(NNC / 128, MM / 128);   // (8, 256)

    // Layer 1: input gates (gathered through sentence) -> recurrence
    gemm_gates<true><<<gemm_grid, 256, 0, stream>>>(
        emb, sentence, w_ih_f1, w_ih_r1, b_ih_f1, b_hh_f1, b_ih_r1, b_hh_r1, gx);
    lstm_rec<<<128, 512, 0, stream>>>(gx, w_hh_f1, w_hh_r1, h0_1, c0_1, out1);

    // Layer 2
    gemm_gates<false><<<gemm_grid, 256, 0, stream>>>(
        out1, nullptr, w_ih_f2, w_ih_r2, b_ih_f2, b_hh_f2, b_ih_r2, b_hh_r2, gx);
    lstm_rec<<<128, 512, 0, stream>>>(gx, w_hh_f2, w_hh_r2, h0_2, c0_2, out2);

    // Projection + fused CRF
    feats_kernel<<<MM / 256, 256, 0, stream>>>(out2, w_out, b_out, feats);
    viterbi_crf<<<NB, 64, 0, stream>>>(feats, masks, trans, (float*)d_out);
}